// Round 16
// baseline (249.385 us; speedup 1.0000x reference)
//
#include <hip/hip_runtime.h>

typedef _Float16 half8 __attribute__((ext_vector_type(8)));
typedef _Float16 half4 __attribute__((ext_vector_type(4)));
typedef _Float16 half2v __attribute__((ext_vector_type(2)));
typedef float floatx4 __attribute__((ext_vector_type(4)));

__device__ __forceinline__ void gl_lds16(const _Float16* g, _Float16* l) {
    __builtin_amdgcn_global_load_lds(
        (const __attribute__((address_space(1))) void*)g,
        (__attribute__((address_space(3))) void*)l, 16, 0, 0);
}

__device__ __forceinline__ half2v cvt_pk(float a, float b) {
    return __builtin_bit_cast(half2v, __builtin_amdgcn_cvt_pkrtz(a, b));
}

__device__ __forceinline__ half2v rcp2(half2v d) {
#if __has_builtin(__builtin_amdgcn_rcph)
    half2v r;
    r[0] = __builtin_amdgcn_rcph(d[0]);
    r[1] = __builtin_amdgcn_rcph(d[1]);
    return r;
#else
    half2v r;
    r[0] = (_Float16)__builtin_amdgcn_rcpf((float)d[0]);
    r[1] = (_Float16)__builtin_amdgcn_rcpf((float)d[1]);
    return r;
#endif
}

__device__ __forceinline__ float dot2acc(half2v a, float acc) {
#if __has_builtin(__builtin_amdgcn_fdot2)
    const half2v one = {(_Float16)1.0f, (_Float16)1.0f};
    return __builtin_amdgcn_fdot2(a, one, acc, false);
#else
    return acc + (float)a[0] + (float)a[1];
#endif
}

// ---------------- fp32 -> fp16 convert: x and w_qkv fused (runs BEFORE gemm_qkv) -
__global__ __launch_bounds__(256) void cvt_xw(const floatx4* __restrict__ x,
                                              const floatx4* __restrict__ wq,
                                              half4* __restrict__ xh,
                                              half4* __restrict__ wqh) {
    int i = blockIdx.x * 256 + threadIdx.x;   // 0..1835007
    floatx4 v;
    half4 h;
    if (i < 1048576) {
        v = x[i];
#pragma unroll
        for (int j = 0; j < 4; ++j) h[j] = (_Float16)v[j];
        xh[i] = h;
    } else {
        int j4 = i - 1048576;
        v = wq[j4];
#pragma unroll
        for (int j = 0; j < 4; ++j) h[j] = (_Float16)v[j];
        wqh[j4] = h;
    }
}

// wout cvt — MUST run after gemm_qkv (woh aliases wqh)
__global__ __launch_bounds__(256) void cvt_f32_f16(const floatx4* __restrict__ in,
                                                   half4* __restrict__ out, int n4) {
    int i = blockIdx.x * 256 + threadIdx.x;
    if (i >= n4) return;
    floatx4 v = in[i];
    half4 h;
#pragma unroll
    for (int j = 0; j < 4; ++j) h[j] = (_Float16)v[j];
    out[i] = h;
}

// ---------------- GEMM1: qkv = xh @ wqh^T -> head-major q/k/vt (fp16 in/out) -----
// M=4096, N=3072, K=1024. 128x128 tile, BK=32, 256 thr, DMA staging.
__global__ __launch_bounds__(256) void gemm_qkv(const _Float16* __restrict__ A,
                                                const _Float16* __restrict__ B,
                                                _Float16* __restrict__ qh,
                                                _Float16* __restrict__ kh,
                                                _Float16* __restrict__ vth) {
    const int K = 1024;
    __shared__ _Float16 SH[128 * 68];   // As 8KB | Bs 8KB; epilogue 128x68
    _Float16* As = SH;
    _Float16* Bs = SH + 4096;
    const int t = threadIdx.x;
    const int lane = t & 63, w = t >> 6;
    const int l15 = lane & 15, quad = lane >> 4;
    const int wm = w >> 1, wn = w & 1;
    const int m0 = blockIdx.y * 128, n0 = blockIdx.x * 128;

    floatx4 acc[4][4];
    const floatx4 zf = {0.f, 0.f, 0.f, 0.f};
#pragma unroll
    for (int i = 0; i < 4; ++i)
#pragma unroll
        for (int j = 0; j < 4; ++j) acc[i][j] = zf;

    for (int kt = 0; kt < K; kt += 32) {
        __syncthreads();
#pragma unroll
        for (int it = 0; it < 2; ++it) {    // 512 chunks of 16B per matrix
            int cc = it * 256 + t;
            int row = cc >> 2, kc = cc & 3;
            gl_lds16(&A[(size_t)(m0 + row) * K + kt + kc * 8], &As[cc * 8]);
            gl_lds16(&B[(size_t)(n0 + row) * K + kt + kc * 8], &Bs[cc * 8]);
        }
        __syncthreads();
        half8 af[4], bfr[4];
#pragma unroll
        for (int i = 0; i < 4; ++i)
            af[i] = *(const half8*)&As[(wm * 64 + i * 16 + l15) * 32 + quad * 8];
#pragma unroll
        for (int i = 0; i < 4; ++i)
            bfr[i] = *(const half8*)&Bs[(wn * 64 + i * 16 + l15) * 32 + quad * 8];
#pragma unroll
        for (int mi = 0; mi < 4; ++mi)
#pragma unroll
            for (int ni = 0; ni < 4; ++ni)
                acc[mi][ni] = __builtin_amdgcn_mfma_f32_16x16x32_f16(af[mi], bfr[ni],
                                                                     acc[mi][ni], 0, 0, 0);
    }

    // ---- epilogue: two 128x64 col-halves staged through LDS, coalesced writes ----
    const int b = m0 >> 11, s0 = m0 & 2047;
#pragma unroll
    for (int hf = 0; hf < 2; ++hf) {
        __syncthreads();
        if (wn == hf) {
#pragma unroll
            for (int mi = 0; mi < 4; ++mi)
#pragma unroll
                for (int ni = 0; ni < 4; ++ni)
#pragma unroll
                    for (int r = 0; r < 4; ++r)
                        SH[(wm * 64 + mi * 16 + quad * 4 + r) * 68 + ni * 16 + l15] =
                            (_Float16)acc[mi][ni][r];
        }
        __syncthreads();
        const int cbase = n0 + hf * 64;
        if (n0 < 2048) {
            const int hh = (cbase & 1023) >> 6;
            _Float16* dst = (n0 < 1024 ? qh : kh) + (size_t)((b << 4) | hh) * 131072;
#pragma unroll
            for (int it = 0; it < 4; ++it) {
                int cc = it * 256 + t;
                int r = cc >> 3, c8 = cc & 7;
                half4 lo = *(const half4*)&SH[r * 68 + c8 * 8];
                half4 hi = *(const half4*)&SH[r * 68 + c8 * 8 + 4];
                half8 v;
#pragma unroll
                for (int j = 0; j < 4; ++j) { v[j] = lo[j]; v[j + 4] = hi[j]; }
                *(half8*)&dst[(size_t)(s0 + r) * 64 + c8 * 8] = v;
            }
        } else {
            const int hh = (cbase - 2048) >> 6;
            _Float16* dst = vth + (size_t)((b << 4) | hh) * 131072;
#pragma unroll
            for (int it = 0; it < 4; ++it) {
                int cc = it * 256 + t;
                int d = cc >> 4, s8 = cc & 15;
                half8 v;
#pragma unroll
                for (int j = 0; j < 8; ++j) v[j] = SH[(s8 * 8 + j) * 68 + d];
                *(half8*)&dst[(size_t)d * 2048 + s0 + s8 * 8] = v;
            }
        }
    }
}

// ---------------- GEMM2: out = aoh @ woh^T + b_out -> fp32 -----------------------
// M=4096, N=1024, K=1024. 64x128 tile, BK=32, 256 thr, DMA staging.
__global__ __launch_bounds__(256) void gemm_out(const _Float16* __restrict__ A,
                                                const _Float16* __restrict__ B,
                                                float* __restrict__ C,
                                                const float* __restrict__ bias) {
    const int K = 1024, N = 1024;
    __shared__ _Float16 SH[6144];   // As 64x32 (4KB) | Bs 128x32 (8KB)
    _Float16* As = SH;
    _Float16* Bs = SH + 2048;
    const int t = threadIdx.x;
    const int lane = t & 63, w = t >> 6;
    const int l15 = lane & 15, quad = lane >> 4;
    const int wm = w >> 1, wn = w & 1;
    const int m0 = blockIdx.y * 64, n0 = blockIdx.x * 128;

    floatx4 acc[2][4];
    const floatx4 zf = {0.f, 0.f, 0.f, 0.f};
#pragma unroll
    for (int i = 0; i < 2; ++i)
#pragma unroll
        for (int j = 0; j < 4; ++j) acc[i][j] = zf;

    for (int kt = 0; kt < K; kt += 32) {
        __syncthreads();
        {   // A: 256 chunks of 16B
            int row = t >> 2, kc = t & 3;
            gl_lds16(&A[(size_t)(m0 + row) * K + kt + kc * 8], &As[t * 8]);
        }
#pragma unroll
        for (int it = 0; it < 2; ++it) {    // B: 512 chunks of 16B
            int cc = it * 256 + t;
            int row = cc >> 2, kc = cc & 3;
            gl_lds16(&B[(size_t)(n0 + row) * K + kt + kc * 8], &Bs[cc * 8]);
        }
        __syncthreads();
        half8 af[2], bfr[4];
#pragma unroll
        for (int i = 0; i < 2; ++i)
            af[i] = *(const half8*)&As[(wm * 32 + i * 16 + l15) * 32 + quad * 8];
#pragma unroll
        for (int i = 0; i < 4; ++i)
            bfr[i] = *(const half8*)&Bs[(wn * 64 + i * 16 + l15) * 32 + quad * 8];
#pragma unroll
        for (int mi = 0; mi < 2; ++mi)
#pragma unroll
            for (int ni = 0; ni < 4; ++ni)
                acc[mi][ni] = __builtin_amdgcn_mfma_f32_16x16x32_f16(af[mi], bfr[ni],
                                                                     acc[mi][ni], 0, 0, 0);
    }

#pragma unroll
    for (int mi = 0; mi < 2; ++mi) {
#pragma unroll
        for (int ni = 0; ni < 4; ++ni) {
            int col = n0 + wn * 64 + ni * 16 + l15;
            float bv = bias[col];
#pragma unroll
            for (int r = 0; r < 4; ++r) {
                int row = m0 + wm * 32 + mi * 16 + quad * 4 + r;
                C[(size_t)row * N + col] = acc[mi][ni][r] + bv;
            }
        }
    }
}

// ---------------- fused two-pass stablemax attention (S^T form, q-tile 64) -------
// grid (S/64, B*H), 256 threads = 4 waves; wave w owns 16 q rows (w*16 + l15).
// 1024 blocks -> 4 blocks/CU -> 4 waves/SIMD. Q pre-scaled by 0.125 in registers;
// s3 in packed fp16; P never touches LDS
// (permuted-key PV: key(c,quad,j) = c*32 + (j>>2)*16 + quad*4 + (j&3)).
__global__ __launch_bounds__(256) void attn_kernel(const _Float16* __restrict__ qh,
                                                   const _Float16* __restrict__ kh,
                                                   const _Float16* __restrict__ vth,
                                                   _Float16* __restrict__ out) {
    __shared__ _Float16 SM[2 * 64 * 72];   // Ks | VTs (9 KB each); reused as O-stage
    _Float16* Ks = SM;
    _Float16* VTs = SM + 64 * 72;

    const int t = threadIdx.x;
    const int lane = t & 63, w = t >> 6;
    const int l15 = lane & 15, quad = lane >> 4;
    const int q0 = blockIdx.x * 64;
    const int bh = blockIdx.y;
    const int b = bh >> 4, h = bh & 15;

    const _Float16* Qp = qh + (size_t)bh * 131072 + q0 * 64;
    const _Float16* Kp = kh + (size_t)bh * 131072;
    const _Float16* VTp = vth + (size_t)bh * 131072;

    const floatx4 zf = {0.f, 0.f, 0.f, 0.f};
    const int qrow = w * 16 + l15;   // this lane's q row within the tile

    half8 qf[2];   // [kk], pre-scaled by 0.125
#pragma unroll
    for (int kk = 0; kk < 2; ++kk) {
        half8 q = *(const half8*)&Qp[qrow * 64 + kk * 32 + quad * 8];
#pragma unroll
        for (int j = 0; j < 8; ++j) q[j] = q[j] * (_Float16)0.125f;
        qf[kk] = q;
    }

    // ---------------- pass 1: row max over (scaled) scores --------------------
    float rmax = -1.0e30f;

    for (int kt = 0; kt < 2048; kt += 64) {
        __syncthreads();
#pragma unroll
        for (int it = 0; it < 2; ++it) {
            int cc = it * 256 + t;
            int r = cc >> 3, c8 = cc & 7;
            *(half8*)&Ks[r * 72 + c8 * 8] = *(const half8*)&Kp[kt * 64 + cc * 8];
        }
        __syncthreads();
        floatx4 sa[4];
#pragma unroll
        for (int T = 0; T < 4; ++T) sa[T] = zf;
#pragma unroll
        for (int kk = 0; kk < 2; ++kk) {
            half8 kf[4];
#pragma unroll
            for (int T = 0; T < 4; ++T)
                kf[T] = *(const half8*)&Ks[(T * 16 + l15) * 72 + kk * 32 + quad * 8];
#pragma unroll
            for (int T = 0; T < 4; ++T)
                sa[T] = __builtin_amdgcn_mfma_f32_16x16x32_f16(kf[T], qf[kk], sa[T], 0, 0, 0);
        }
#pragma unroll
        for (int T = 0; T < 4; ++T)
#pragma unroll
            for (int r = 0; r < 4; ++r)
                rmax = fmaxf(rmax, sa[T][r]);
    }
    rmax = fmaxf(rmax, __shfl_xor(rmax, 16, 64));
    rmax = fmaxf(rmax, __shfl_xor(rmax, 32, 64));
    const float xm = -rmax;

    // ---------------- pass 2: p = s3(x); Sum p; P·V ---------------------------
    const half2v cA = {(_Float16)(-1.0f / 6.0f), (_Float16)(-1.0f / 6.0f)};
    const half2v cB = {(_Float16)0.5f, (_Float16)0.5f};
    const half2v cC = {(_Float16)-1.0f, (_Float16)-1.0f};
    const half2v cD = {(_Float16)1.0f, (_Float16)1.0f};

    float rsum = 0.f;
    floatx4 oacc[4];
#pragma unroll
    for (int i = 0; i < 4; ++i) oacc[i] = zf;

    for (int kt = 0; kt < 2048; kt += 64) {
        __syncthreads();
#pragma unroll
        for (int it = 0; it < 2; ++it) {
            int cc = it * 256 + t;
            int r = cc >> 3, c8 = cc & 7;
            *(half8*)&Ks[r * 72 + c8 * 8] = *(const half8*)&Kp[kt * 64 + cc * 8];
            *(half8*)&VTs[r * 72 + c8 * 8] =
                *(const half8*)&VTp[(size_t)r * 2048 + kt + c8 * 8];
        }
        __syncthreads();
        floatx4 sa[4];
#pragma unroll
        for (int T = 0; T < 4; ++T) sa[T] = zf;
#pragma unroll
        for (int kk = 0; kk < 2; ++kk) {
            half8 kf[4];
#pragma unroll
            for (int T = 0; T < 4; ++T)
                kf[T] = *(const half8*)&Ks[(T * 16 + l15) * 72 + kk * 32 + quad * 8];
#pragma unroll
            for (int T = 0; T < 4; ++T)
                sa[T] = __builtin_amdgcn_mfma_f32_16x16x32_f16(kf[T], qf[kk], sa[T], 0, 0, 0);
        }
        // PV with permuted key order; s3 in packed fp16 straight into pb
#pragma unroll
        for (int c = 0; c < 2; ++c) {
            half8 vf[4];
#pragma unroll
            for (int di = 0; di < 4; ++di) {
                half4 lo = *(const half4*)&VTs[(di * 16 + l15) * 72 + c * 32 + 4 * quad];
                half4 hi = *(const half4*)&VTs[(di * 16 + l15) * 72 + c * 32 + 16 + 4 * quad];
                half8 vv;
#pragma unroll
                for (int j = 0; j < 4; ++j) { vv[j] = lo[j]; vv[j + 4] = hi[j]; }
                vf[di] = vv;
            }
            half8 pb;
#pragma unroll
            for (int m = 0; m < 4; ++m) {
                int T = 2 * c + (m >> 1);
                int r0 = (m & 1) * 2;
                half2v x2 = cvt_pk(sa[T][r0] + xm, sa[T][r0 + 1] + xm);
                half2v hp = __builtin_elementwise_fma(x2, cA, cB);
                hp = __builtin_elementwise_fma(x2, hp, cC);
                hp = __builtin_elementwise_fma(x2, hp, cD);
                half2v p2 = rcp2(hp);
                rsum = dot2acc(p2, rsum);
                pb[2 * m] = p2[0];
                pb[2 * m + 1] = p2[1];
            }
#pragma unroll
            for (int di = 0; di < 4; ++di)
                oacc[di] = __builtin_amdgcn_mfma_f32_16x16x32_f16(vf[di], pb,
                                                                 oacc[di], 0, 0, 0);
        }
    }

    rsum += __shfl_xor(rsum, 16, 64);
    rsum += __shfl_xor(rsum, 32, 64);
    const float inv = 1.0f / rsum;

    // stage O (q-major, 64 rows x stride 72) into LDS for coalesced global write
    __syncthreads();
    _Float16* Os = SM;
#pragma unroll
    for (int di = 0; di < 4; ++di) {
        half4 hv;
#pragma unroll
        for (int r = 0; r < 4; ++r) hv[r] = (_Float16)(oacc[di][r] * inv);
        *(half4*)&Os[qrow * 72 + di * 16 + quad * 4] = hv;
    }
    __syncthreads();
    _Float16* Op = out + (size_t)(b * 2048 + q0) * 1024 + h * 64;
#pragma unroll
    for (int it = 0; it < 2; ++it) {
        int cc = it * 256 + t;
        int r = cc >> 3, c8 = cc & 7;
        *(half8*)&Op[(size_t)r * 1024 + c8 * 8] = *(const half8*)&Os[r * 72 + c8 * 8];
    }
}

// ---------------- launch ---------------------------------------------------------
extern "C" void kernel_launch(void* const* d_in, const int* in_sizes, int n_in,
                              void* d_out, int out_size, void* d_ws, size_t ws_size,
                              hipStream_t stream) {
    const float* x_f = (const float*)d_in[0];     // [2,2048,1024] fp32
    const float* wqkv_f = (const float*)d_in[1];  // [3072,1024] fp32
    const float* wout_f = (const float*)d_in[2];  // [1024,1024] fp32
    const float* bias_f = (const float*)d_in[3];  // [1024] fp32

    // workspace: 38 MB, with aliasing (aoh reuses xh; woh reuses wqh).
    // ORDERING CONSTRAINT: woh is written only AFTER gemm_qkv consumes wqh.
    char* ws = (char*)d_ws;
    _Float16* xh = (_Float16*)(ws);                   // [4096][1024] f16, 8 MB
    _Float16* aoh = xh;                               // alias: live after gemm_qkv
    _Float16* wqh = (_Float16*)(ws + 8388608);        // [3072][1024] f16, 6 MB
    _Float16* woh = wqh;                              // alias: live after gemm_qkv
    _Float16* qh = (_Float16*)(ws + 14680064);        // [32][2048][64] f16, 8 MB
    _Float16* kh = (_Float16*)(ws + 23068672);        // [32][2048][64] f16, 8 MB
    _Float16* vth = (_Float16*)(ws + 31457280);       // [32][64][2048] f16, 8 MB

    cvt_xw<<<7168, 256, 0, stream>>>((const floatx4*)x_f, (const floatx4*)wqkv_f,
                                     (half4*)xh, (half4*)wqh);
    gemm_qkv<<<dim3(24, 32), 256, 0, stream>>>(xh, wqh, qh, kh, vth);
    cvt_f32_f16<<<1024, 256, 0, stream>>>((const floatx4*)wout_f, (half4*)woh, 262144);
    attn_kernel<<<dim3(32, 32), 256, 0, stream>>>(qh, kh, vth, aoh);
    gemm_out<<<dim3(8, 64), 256, 0, stream>>>(aoh, woh, (float*)d_out, bias_f);
}

// Round 17
// 240.920 us; speedup vs baseline: 1.0351x; 1.0351x over previous
//
#include <hip/hip_runtime.h>

typedef _Float16 half8 __attribute__((ext_vector_type(8)));
typedef _Float16 half4 __attribute__((ext_vector_type(4)));
typedef _Float16 half2v __attribute__((ext_vector_type(2)));
typedef float floatx4 __attribute__((ext_vector_type(4)));

__device__ __forceinline__ void gl_lds16(const _Float16* g, _Float16* l) {
    __builtin_amdgcn_global_load_lds(
        (const __attribute__((address_space(1))) void*)g,
        (__attribute__((address_space(3))) void*)l, 16, 0, 0);
}

__device__ __forceinline__ half2v cvt_pk(float a, float b) {
    return __builtin_bit_cast(half2v, __builtin_amdgcn_cvt_pkrtz(a, b));
}

__device__ __forceinline__ half2v rcp2(half2v d) {
#if __has_builtin(__builtin_amdgcn_rcph)
    half2v r;
    r[0] = __builtin_amdgcn_rcph(d[0]);
    r[1] = __builtin_amdgcn_rcph(d[1]);
    return r;
#else
    half2v r;
    r[0] = (_Float16)__builtin_amdgcn_rcpf((float)d[0]);
    r[1] = (_Float16)__builtin_amdgcn_rcpf((float)d[1]);
    return r;
#endif
}

__device__ __forceinline__ float dot2acc(half2v a, float acc) {
#if __has_builtin(__builtin_amdgcn_fdot2)
    const half2v one = {(_Float16)1.0f, (_Float16)1.0f};
    return __builtin_amdgcn_fdot2(a, one, acc, false);
#else
    return acc + (float)a[0] + (float)a[1];
#endif
}

// ---------------- fp32 -> fp16 convert: x and w_qkv fused (runs BEFORE gemm_qkv) -
__global__ __launch_bounds__(256) void cvt_xw(const floatx4* __restrict__ x,
                                              const floatx4* __restrict__ wq,
                                              half4* __restrict__ xh,
                                              half4* __restrict__ wqh) {
    int i = blockIdx.x * 256 + threadIdx.x;   // 0..1835007
    floatx4 v;
    half4 h;
    if (i < 1048576) {
        v = x[i];
#pragma unroll
        for (int j = 0; j < 4; ++j) h[j] = (_Float16)v[j];
        xh[i] = h;
    } else {
        int j4 = i - 1048576;
        v = wq[j4];
#pragma unroll
        for (int j = 0; j < 4; ++j) h[j] = (_Float16)v[j];
        wqh[j4] = h;
    }
}

// wout cvt — MUST run after gemm_qkv (woh aliases wqh)
__global__ __launch_bounds__(256) void cvt_f32_f16(const floatx4* __restrict__ in,
                                                   half4* __restrict__ out, int n4) {
    int i = blockIdx.x * 256 + threadIdx.x;
    if (i >= n4) return;
    floatx4 v = in[i];
    half4 h;
#pragma unroll
    for (int j = 0; j < 4; ++j) h[j] = (_Float16)v[j];
    out[i] = h;
}

// ---------------- GEMM1: qkv = xh @ wqh^T -> head-major q/k/vt (fp16 in/out) -----
// M=4096, N=3072, K=1024. 128x128 tile, BK=32, 256 thr, DMA staging.
__global__ __launch_bounds__(256) void gemm_qkv(const _Float16* __restrict__ A,
                                                const _Float16* __restrict__ B,
                                                _Float16* __restrict__ qh,
                                                _Float16* __restrict__ kh,
                                                _Float16* __restrict__ vth) {
    const int K = 1024;
    __shared__ _Float16 SH[128 * 68];   // As 8KB | Bs 8KB; epilogue 128x68
    _Float16* As = SH;
    _Float16* Bs = SH + 4096;
    const int t = threadIdx.x;
    const int lane = t & 63, w = t >> 6;
    const int l15 = lane & 15, quad = lane >> 4;
    const int wm = w >> 1, wn = w & 1;
    const int m0 = blockIdx.y * 128, n0 = blockIdx.x * 128;

    floatx4 acc[4][4];
    const floatx4 zf = {0.f, 0.f, 0.f, 0.f};
#pragma unroll
    for (int i = 0; i < 4; ++i)
#pragma unroll
        for (int j = 0; j < 4; ++j) acc[i][j] = zf;

    for (int kt = 0; kt < K; kt += 32) {
        __syncthreads();
#pragma unroll
        for (int it = 0; it < 2; ++it) {    // 512 chunks of 16B per matrix
            int cc = it * 256 + t;
            int row = cc >> 2, kc = cc & 3;
            gl_lds16(&A[(size_t)(m0 + row) * K + kt + kc * 8], &As[cc * 8]);
            gl_lds16(&B[(size_t)(n0 + row) * K + kt + kc * 8], &Bs[cc * 8]);
        }
        __syncthreads();
        half8 af[4], bfr[4];
#pragma unroll
        for (int i = 0; i < 4; ++i)
            af[i] = *(const half8*)&As[(wm * 64 + i * 16 + l15) * 32 + quad * 8];
#pragma unroll
        for (int i = 0; i < 4; ++i)
            bfr[i] = *(const half8*)&Bs[(wn * 64 + i * 16 + l15) * 32 + quad * 8];
#pragma unroll
        for (int mi = 0; mi < 4; ++mi)
#pragma unroll
            for (int ni = 0; ni < 4; ++ni)
                acc[mi][ni] = __builtin_amdgcn_mfma_f32_16x16x32_f16(af[mi], bfr[ni],
                                                                     acc[mi][ni], 0, 0, 0);
    }

    // ---- epilogue: two 128x64 col-halves staged through LDS, coalesced writes ----
    const int b = m0 >> 11, s0 = m0 & 2047;
#pragma unroll
    for (int hf = 0; hf < 2; ++hf) {
        __syncthreads();
        if (wn == hf) {
#pragma unroll
            for (int mi = 0; mi < 4; ++mi)
#pragma unroll
                for (int ni = 0; ni < 4; ++ni)
#pragma unroll
                    for (int r = 0; r < 4; ++r)
                        SH[(wm * 64 + mi * 16 + quad * 4 + r) * 68 + ni * 16 + l15] =
                            (_Float16)acc[mi][ni][r];
        }
        __syncthreads();
        const int cbase = n0 + hf * 64;
        if (n0 < 2048) {
            const int hh = (cbase & 1023) >> 6;
            _Float16* dst = (n0 < 1024 ? qh : kh) + (size_t)((b << 4) | hh) * 131072;
#pragma unroll
            for (int it = 0; it < 4; ++it) {
                int cc = it * 256 + t;
                int r = cc >> 3, c8 = cc & 7;
                half4 lo = *(const half4*)&SH[r * 68 + c8 * 8];
                half4 hi = *(const half4*)&SH[r * 68 + c8 * 8 + 4];
                half8 v;
#pragma unroll
                for (int j = 0; j < 4; ++j) { v[j] = lo[j]; v[j + 4] = hi[j]; }
                *(half8*)&dst[(size_t)(s0 + r) * 64 + c8 * 8] = v;
            }
        } else {
            const int hh = (cbase - 2048) >> 6;
            _Float16* dst = vth + (size_t)((b << 4) | hh) * 131072;
#pragma unroll
            for (int it = 0; it < 4; ++it) {
                int cc = it * 256 + t;
                int d = cc >> 4, s8 = cc & 15;
                half8 v;
#pragma unroll
                for (int j = 0; j < 8; ++j) v[j] = SH[(s8 * 8 + j) * 68 + d];
                *(half8*)&dst[(size_t)d * 2048 + s0 + s8 * 8] = v;
            }
        }
    }
}

// ---------------- GEMM2: out = aoh @ woh^T + b_out -> fp32 -----------------------
// M=4096, N=1024, K=1024. 64x128 tile, BK=32, 256 thr, DMA staging.
__global__ __launch_bounds__(256) void gemm_out(const _Float16* __restrict__ A,
                                                const _Float16* __restrict__ B,
                                                float* __restrict__ C,
                                                const float* __restrict__ bias) {
    const int K = 1024, N = 1024;
    __shared__ _Float16 SH[6144];   // As 64x32 (4KB) | Bs 128x32 (8KB)
    _Float16* As = SH;
    _Float16* Bs = SH + 2048;
    const int t = threadIdx.x;
    const int lane = t & 63, w = t >> 6;
    const int l15 = lane & 15, quad = lane >> 4;
    const int wm = w >> 1, wn = w & 1;
    const int m0 = blockIdx.y * 64, n0 = blockIdx.x * 128;

    floatx4 acc[2][4];
    const floatx4 zf = {0.f, 0.f, 0.f, 0.f};
#pragma unroll
    for (int i = 0; i < 2; ++i)
#pragma unroll
        for (int j = 0; j < 4; ++j) acc[i][j] = zf;

    for (int kt = 0; kt < K; kt += 32) {
        __syncthreads();
        {   // A: 256 chunks of 16B
            int row = t >> 2, kc = t & 3;
            gl_lds16(&A[(size_t)(m0 + row) * K + kt + kc * 8], &As[t * 8]);
        }
#pragma unroll
        for (int it = 0; it < 2; ++it) {    // B: 512 chunks of 16B
            int cc = it * 256 + t;
            int row = cc >> 2, kc = cc & 3;
            gl_lds16(&B[(size_t)(n0 + row) * K + kt + kc * 8], &Bs[cc * 8]);
        }
        __syncthreads();
        half8 af[2], bfr[4];
#pragma unroll
        for (int i = 0; i < 2; ++i)
            af[i] = *(const half8*)&As[(wm * 32 + i * 16 + l15) * 32 + quad * 8];
#pragma unroll
        for (int i = 0; i < 4; ++i)
            bfr[i] = *(const half8*)&Bs[(wn * 64 + i * 16 + l15) * 32 + quad * 8];
#pragma unroll
        for (int mi = 0; mi < 2; ++mi)
#pragma unroll
            for (int ni = 0; ni < 4; ++ni)
                acc[mi][ni] = __builtin_amdgcn_mfma_f32_16x16x32_f16(af[mi], bfr[ni],
                                                                     acc[mi][ni], 0, 0, 0);
    }

#pragma unroll
    for (int mi = 0; mi < 2; ++mi) {
#pragma unroll
        for (int ni = 0; ni < 4; ++ni) {
            int col = n0 + wn * 64 + ni * 16 + l15;
            float bv = bias[col];
#pragma unroll
            for (int r = 0; r < 4; ++r) {
                int row = m0 + wm * 32 + mi * 16 + quad * 4 + r;
                C[(size_t)row * N + col] = acc[mi][ni][r] + bv;
            }
        }
    }
}

// ---------------- fused two-pass stablemax attention (S^T, 128-key tiles) --------
// grid (S/128, B*H), 256 threads. Wave w owns 32 q rows (w*32 + nh*16 + l15) —
// the measured-best kf amortization (r14). 128-key tiles halve barrier count
// (r9's idea) with scores consumed per-T/per-c so only sa[2][2] is live (fixes
// r9's register blowup). Q pre-scaled by 0.125; s3 in packed fp16; P never
// touches LDS (permuted-key PV: key(c,quad,j) = c*32 + (j>>2)*16 + quad*4 + (j&3)).
__global__ __launch_bounds__(256) void attn_kernel(const _Float16* __restrict__ qh,
                                                   const _Float16* __restrict__ kh,
                                                   const _Float16* __restrict__ vth,
                                                   _Float16* __restrict__ out) {
    __shared__ _Float16 SM[128 * 72 + 64 * 136];   // Ks 18.4KB | VTs 17.4KB
    _Float16* Ks = SM;
    _Float16* VTs = SM + 128 * 72;

    const int t = threadIdx.x;
    const int lane = t & 63, w = t >> 6;
    const int l15 = lane & 15, quad = lane >> 4;
    const int q0 = blockIdx.x * 128;
    const int bh = blockIdx.y;
    const int b = bh >> 4, h = bh & 15;

    const _Float16* Qp = qh + (size_t)bh * 131072 + q0 * 64;
    const _Float16* Kp = kh + (size_t)bh * 131072;
    const _Float16* VTp = vth + (size_t)bh * 131072;

    const floatx4 zf = {0.f, 0.f, 0.f, 0.f};

    half8 qf[2][2];   // [nh][kk], pre-scaled by 0.125
#pragma unroll
    for (int nh = 0; nh < 2; ++nh)
#pragma unroll
        for (int kk = 0; kk < 2; ++kk) {
            half8 q = *(const half8*)&Qp[(w * 32 + nh * 16 + l15) * 64 + kk * 32 + quad * 8];
#pragma unroll
            for (int j = 0; j < 8; ++j) q[j] = q[j] * (_Float16)0.125f;
            qf[nh][kk] = q;
        }

    // ---------------- pass 1: row max, 128-key tiles, per-T consumption -------
    float rmax[2] = {-1.0e30f, -1.0e30f};

    for (int kt = 0; kt < 2048; kt += 128) {
        __syncthreads();
#pragma unroll
        for (int it = 0; it < 4; ++it) {   // K tile 128x64: 1024 chunks of 8
            int cc = it * 256 + t;
            int r = cc >> 3, c8 = cc & 7;
            *(half8*)&Ks[r * 72 + c8 * 8] = *(const half8*)&Kp[(size_t)(kt + r) * 64 + c8 * 8];
        }
        __syncthreads();
#pragma unroll
        for (int T = 0; T < 8; ++T) {
            half8 kf0 = *(const half8*)&Ks[(T * 16 + l15) * 72 + quad * 8];
            half8 kf1 = *(const half8*)&Ks[(T * 16 + l15) * 72 + 32 + quad * 8];
            floatx4 sa0 = __builtin_amdgcn_mfma_f32_16x16x32_f16(kf0, qf[0][0], zf, 0, 0, 0);
            sa0 = __builtin_amdgcn_mfma_f32_16x16x32_f16(kf1, qf[0][1], sa0, 0, 0, 0);
            floatx4 sa1 = __builtin_amdgcn_mfma_f32_16x16x32_f16(kf0, qf[1][0], zf, 0, 0, 0);
            sa1 = __builtin_amdgcn_mfma_f32_16x16x32_f16(kf1, qf[1][1], sa1, 0, 0, 0);
#pragma unroll
            for (int r = 0; r < 4; ++r) {
                rmax[0] = fmaxf(rmax[0], sa0[r]);
                rmax[1] = fmaxf(rmax[1], sa1[r]);
            }
        }
    }
#pragma unroll
    for (int nh = 0; nh < 2; ++nh) {
        rmax[nh] = fmaxf(rmax[nh], __shfl_xor(rmax[nh], 16, 64));
        rmax[nh] = fmaxf(rmax[nh], __shfl_xor(rmax[nh], 32, 64));
    }
    const float xm[2] = {-rmax[0], -rmax[1]};

    // ---------------- pass 2: 128-key tiles, per-c s3+PV -----------------------
    const half2v cA = {(_Float16)(-1.0f / 6.0f), (_Float16)(-1.0f / 6.0f)};
    const half2v cB = {(_Float16)0.5f, (_Float16)0.5f};
    const half2v cC = {(_Float16)-1.0f, (_Float16)-1.0f};
    const half2v cD = {(_Float16)1.0f, (_Float16)1.0f};

    float rsum[2] = {0.f, 0.f};
    floatx4 oacc[4][2];
#pragma unroll
    for (int i = 0; i < 4; ++i) { oacc[i][0] = zf; oacc[i][1] = zf; }

    for (int kt = 0; kt < 2048; kt += 128) {
        __syncthreads();
#pragma unroll
        for (int it = 0; it < 4; ++it) {
            int cc = it * 256 + t;
            int r = cc >> 3, c8 = cc & 7;
            *(half8*)&Ks[r * 72 + c8 * 8] = *(const half8*)&Kp[(size_t)(kt + r) * 64 + c8 * 8];
            int d = cc >> 4, k8 = cc & 15;
            *(half8*)&VTs[d * 136 + k8 * 8] =
                *(const half8*)&VTp[(size_t)d * 2048 + kt + k8 * 8];
        }
        __syncthreads();
#pragma unroll
        for (int c = 0; c < 4; ++c) {
            // scores for T = 2c, 2c+1 (only these are needed for this c-block)
            half8 kfa0 = *(const half8*)&Ks[((2 * c) * 16 + l15) * 72 + quad * 8];
            half8 kfa1 = *(const half8*)&Ks[((2 * c) * 16 + l15) * 72 + 32 + quad * 8];
            half8 kfb0 = *(const half8*)&Ks[((2 * c + 1) * 16 + l15) * 72 + quad * 8];
            half8 kfb1 = *(const half8*)&Ks[((2 * c + 1) * 16 + l15) * 72 + 32 + quad * 8];
            floatx4 sa[2][2];   // [Tloc][nh]
#pragma unroll
            for (int nh = 0; nh < 2; ++nh) {
                sa[0][nh] = __builtin_amdgcn_mfma_f32_16x16x32_f16(kfa0, qf[nh][0], zf, 0, 0, 0);
                sa[0][nh] = __builtin_amdgcn_mfma_f32_16x16x32_f16(kfa1, qf[nh][1], sa[0][nh], 0, 0, 0);
                sa[1][nh] = __builtin_amdgcn_mfma_f32_16x16x32_f16(kfb0, qf[nh][0], zf, 0, 0, 0);
                sa[1][nh] = __builtin_amdgcn_mfma_f32_16x16x32_f16(kfb1, qf[nh][1], sa[1][nh], 0, 0, 0);
            }
            half8 vf[4];
#pragma unroll
            for (int di = 0; di < 4; ++di) {
                half4 lo = *(const half4*)&VTs[(di * 16 + l15) * 136 + c * 32 + 4 * quad];
                half4 hi = *(const half4*)&VTs[(di * 16 + l15) * 136 + c * 32 + 16 + 4 * quad];
                half8 vv;
#pragma unroll
                for (int j = 0; j < 4; ++j) { vv[j] = lo[j]; vv[j + 4] = hi[j]; }
                vf[di] = vv;
            }
#pragma unroll
            for (int nh = 0; nh < 2; ++nh) {
                half8 pb;
#pragma unroll
                for (int m = 0; m < 4; ++m) {
                    int Tl = m >> 1;
                    int r0 = (m & 1) * 2;
                    half2v x2 = cvt_pk(sa[Tl][nh][r0] + xm[nh],
                                       sa[Tl][nh][r0 + 1] + xm[nh]);
                    half2v hp = __builtin_elementwise_fma(x2, cA, cB);
                    hp = __builtin_elementwise_fma(x2, hp, cC);
                    hp = __builtin_elementwise_fma(x2, hp, cD);
                    half2v p2 = rcp2(hp);
                    rsum[nh] = dot2acc(p2, rsum[nh]);
                    pb[2 * m] = p2[0];
                    pb[2 * m + 1] = p2[1];
                }
#pragma unroll
                for (int di = 0; di < 4; ++di)
                    oacc[di][nh] = __builtin_amdgcn_mfma_f32_16x16x32_f16(vf[di], pb,
                                                                         oacc[di][nh], 0, 0, 0);
            }
        }
    }

#pragma unroll
    for (int nh = 0; nh < 2; ++nh) {
        rsum[nh] += __shfl_xor(rsum[nh], 16, 64);
        rsum[nh] += __shfl_xor(rsum[nh], 32, 64);
    }
    const float inv[2] = {1.0f / rsum[0], 1.0f / rsum[1]};

    __syncthreads();
    _Float16* Os = SM;   // 128 rows x stride 72 fits in Ks region
#pragma unroll
    for (int di = 0; di < 4; ++di) {
#pragma unroll
        for (int nh = 0; nh < 2; ++nh) {
            half4 hv;
#pragma unroll
            for (int r = 0; r < 4; ++r) hv[r] = (_Float16)(oacc[di][nh][r] * inv[nh]);
            *(half4*)&Os[(w * 32 + nh * 16 + l15) * 72 + di * 16 + quad * 4] = hv;
        }
    }
    __syncthreads();
    _Float16* Op = out + (size_t)(b * 2048 + q0) * 1024 + h * 64;
#pragma unroll
    for (int it = 0; it < 4; ++it) {
        int cc = it * 256 + t;
        int r = cc >> 3, c8 = cc & 7;
        *(half8*)&Op[(size_t)r * 1024 + c8 * 8] = *(const half8*)&Os[r * 72 + c8 * 8];
    }
}

// ---------------- launch ---------------------------------------------------------
extern "C" void kernel_launch(void* const* d_in, const int* in_sizes, int n_in,
                              void* d_out, int out_size, void* d_ws, size_t ws_size,
                              hipStream_t stream) {
    const float* x_f = (const float*)d_in[0];     // [2,2048,1024] fp32
    const float* wqkv_f = (const float*)d_in[1];  // [3072,1024] fp32
    const float* wout_f = (const float*)d_in[2];  // [1024,1024] fp32
    const float* bias_f = (const float*)d_in[3];  // [1024] fp32

    // workspace: 38 MB, with aliasing (aoh reuses xh; woh reuses wqh).
    // ORDERING CONSTRAINT: woh is written only AFTER gemm_qkv consumes wqh.
    char* ws = (char*)d_ws;
    _Float16* xh = (_Float16*)(ws);                   // [4096][1024] f16, 8 MB
    _Float16* aoh = xh;                               // alias: live after gemm_qkv
    _Float16* wqh = (_Float16*)(ws + 8388608);        // [3072][1024] f16, 6 MB
    _Float16* woh = wqh;                              // alias: live after gemm_qkv
    _Float16* qh = (_Float16*)(ws + 14680064);        // [32][2048][64] f16, 8 MB
    _Float16* kh = (_Float16*)(ws + 23068672);        // [32][2048][64] f16, 8 MB
    _Float16* vth = (_Float16*)(ws + 31457280);       // [32][64][2048] f16, 8 MB

    cvt_xw<<<7168, 256, 0, stream>>>((const floatx4*)x_f, (const floatx4*)wqkv_f,
                                     (half4*)xh, (half4*)wqh);
    gemm_qkv<<<dim3(24, 32), 256, 0, stream>>>(xh, wqh, qh, kh, vth);
    cvt_f32_f16<<<1024, 256, 0, stream>>>((const floatx4*)wout_f, (half4*)woh, 262144);
    attn_kernel<<<dim3(16, 32), 256, 0, stream>>>(qh, kh, vth, aoh);
    gemm_out<<<dim3(8, 64), 256, 0, stream>>>(aoh, woh, (float*)d_out, bias_f);
}

// Round 18
// 215.298 us; speedup vs baseline: 1.1583x; 1.1190x over previous
//
#include <hip/hip_runtime.h>

typedef _Float16 half8 __attribute__((ext_vector_type(8)));
typedef _Float16 half4 __attribute__((ext_vector_type(4)));
typedef _Float16 half2v __attribute__((ext_vector_type(2)));
typedef float floatx4 __attribute__((ext_vector_type(4)));

__device__ __forceinline__ void gl_lds16(const _Float16* g, _Float16* l) {
    __builtin_amdgcn_global_load_lds(
        (const __attribute__((address_space(1))) void*)g,
        (__attribute__((address_space(3))) void*)l, 16, 0, 0);
}

__device__ __forceinline__ half2v cvt_pk(float a, float b) {
    return __builtin_bit_cast(half2v, __builtin_amdgcn_cvt_pkrtz(a, b));
}

__device__ __forceinline__ half2v rcp2(half2v d) {
#if __has_builtin(__builtin_amdgcn_rcph)
    half2v r;
    r[0] = __builtin_amdgcn_rcph(d[0]);
    r[1] = __builtin_amdgcn_rcph(d[1]);
    return r;
#else
    half2v r;
    r[0] = (_Float16)__builtin_amdgcn_rcpf((float)d[0]);
    r[1] = (_Float16)__builtin_amdgcn_rcpf((float)d[1]);
    return r;
#endif
}

__device__ __forceinline__ float dot2acc(half2v a, float acc) {
#if __has_builtin(__builtin_amdgcn_fdot2)
    const half2v one = {(_Float16)1.0f, (_Float16)1.0f};
    return __builtin_amdgcn_fdot2(a, one, acc, false);
#else
    return acc + (float)a[0] + (float)a[1];
#endif
}

// ---------------- fp32 -> fp16 convert: x and w_qkv fused (runs BEFORE gemm_qkv) -
__global__ __launch_bounds__(256) void cvt_xw(const floatx4* __restrict__ x,
                                              const floatx4* __restrict__ wq,
                                              half4* __restrict__ xh,
                                              half4* __restrict__ wqh) {
    int i = blockIdx.x * 256 + threadIdx.x;   // 0..1835007
    floatx4 v;
    half4 h;
    if (i < 1048576) {
        v = x[i];
#pragma unroll
        for (int j = 0; j < 4; ++j) h[j] = (_Float16)v[j];
        xh[i] = h;
    } else {
        int j4 = i - 1048576;
        v = wq[j4];
#pragma unroll
        for (int j = 0; j < 4; ++j) h[j] = (_Float16)v[j];
        wqh[j4] = h;
    }
}

// wout cvt — MUST run after gemm_qkv (woh aliases wqh)
__global__ __launch_bounds__(256) void cvt_f32_f16(const floatx4* __restrict__ in,
                                                   half4* __restrict__ out, int n4) {
    int i = blockIdx.x * 256 + threadIdx.x;
    if (i >= n4) return;
    floatx4 v = in[i];
    half4 h;
#pragma unroll
    for (int j = 0; j < 4; ++j) h[j] = (_Float16)v[j];
    out[i] = h;
}

// ---------------- GEMM1: qkv = xh @ wqh^T -> head-major q/k/vt (fp16 in/out) -----
// M=4096, N=3072, K=1024. 128x128 tile, BK=32, 256 thr, DMA staging.
__global__ __launch_bounds__(256) void gemm_qkv(const _Float16* __restrict__ A,
                                                const _Float16* __restrict__ B,
                                                _Float16* __restrict__ qh,
                                                _Float16* __restrict__ kh,
                                                _Float16* __restrict__ vth) {
    const int K = 1024;
    __shared__ _Float16 SH[128 * 68];   // As 8KB | Bs 8KB; epilogue 128x68
    _Float16* As = SH;
    _Float16* Bs = SH + 4096;
    const int t = threadIdx.x;
    const int lane = t & 63, w = t >> 6;
    const int l15 = lane & 15, quad = lane >> 4;
    const int wm = w >> 1, wn = w & 1;
    const int m0 = blockIdx.y * 128, n0 = blockIdx.x * 128;

    floatx4 acc[4][4];
    const floatx4 zf = {0.f, 0.f, 0.f, 0.f};
#pragma unroll
    for (int i = 0; i < 4; ++i)
#pragma unroll
        for (int j = 0; j < 4; ++j) acc[i][j] = zf;

    for (int kt = 0; kt < K; kt += 32) {
        __syncthreads();
#pragma unroll
        for (int it = 0; it < 2; ++it) {    // 512 chunks of 16B per matrix
            int cc = it * 256 + t;
            int row = cc >> 2, kc = cc & 3;
            gl_lds16(&A[(size_t)(m0 + row) * K + kt + kc * 8], &As[cc * 8]);
            gl_lds16(&B[(size_t)(n0 + row) * K + kt + kc * 8], &Bs[cc * 8]);
        }
        __syncthreads();
        half8 af[4], bfr[4];
#pragma unroll
        for (int i = 0; i < 4; ++i)
            af[i] = *(const half8*)&As[(wm * 64 + i * 16 + l15) * 32 + quad * 8];
#pragma unroll
        for (int i = 0; i < 4; ++i)
            bfr[i] = *(const half8*)&Bs[(wn * 64 + i * 16 + l15) * 32 + quad * 8];
#pragma unroll
        for (int mi = 0; mi < 4; ++mi)
#pragma unroll
            for (int ni = 0; ni < 4; ++ni)
                acc[mi][ni] = __builtin_amdgcn_mfma_f32_16x16x32_f16(af[mi], bfr[ni],
                                                                     acc[mi][ni], 0, 0, 0);
    }

    // ---- epilogue: two 128x64 col-halves staged through LDS, coalesced writes ----
    const int b = m0 >> 11, s0 = m0 & 2047;
#pragma unroll
    for (int hf = 0; hf < 2; ++hf) {
        __syncthreads();
        if (wn == hf) {
#pragma unroll
            for (int mi = 0; mi < 4; ++mi)
#pragma unroll
                for (int ni = 0; ni < 4; ++ni)
#pragma unroll
                    for (int r = 0; r < 4; ++r)
                        SH[(wm * 64 + mi * 16 + quad * 4 + r) * 68 + ni * 16 + l15] =
                            (_Float16)acc[mi][ni][r];
        }
        __syncthreads();
        const int cbase = n0 + hf * 64;
        if (n0 < 2048) {
            const int hh = (cbase & 1023) >> 6;
            _Float16* dst = (n0 < 1024 ? qh : kh) + (size_t)((b << 4) | hh) * 131072;
#pragma unroll
            for (int it = 0; it < 4; ++it) {
                int cc = it * 256 + t;
                int r = cc >> 3, c8 = cc & 7;
                half4 lo = *(const half4*)&SH[r * 68 + c8 * 8];
                half4 hi = *(const half4*)&SH[r * 68 + c8 * 8 + 4];
                half8 v;
#pragma unroll
                for (int j = 0; j < 4; ++j) { v[j] = lo[j]; v[j + 4] = hi[j]; }
                *(half8*)&dst[(size_t)(s0 + r) * 64 + c8 * 8] = v;
            }
        } else {
            const int hh = (cbase - 2048) >> 6;
            _Float16* dst = vth + (size_t)((b << 4) | hh) * 131072;
#pragma unroll
            for (int it = 0; it < 4; ++it) {
                int cc = it * 256 + t;
                int d = cc >> 4, s8 = cc & 15;
                half8 v;
#pragma unroll
                for (int j = 0; j < 8; ++j) v[j] = SH[(s8 * 8 + j) * 68 + d];
                *(half8*)&dst[(size_t)d * 2048 + s0 + s8 * 8] = v;
            }
        }
    }
}

// ---------------- GEMM2: out = aoh @ woh^T + b_out -> fp32 -----------------------
// M=4096, N=1024, K=1024. 64x128 tile, BK=32, 256 thr, DMA staging.
__global__ __launch_bounds__(256) void gemm_out(const _Float16* __restrict__ A,
                                                const _Float16* __restrict__ B,
                                                float* __restrict__ C,
                                                const float* __restrict__ bias) {
    const int K = 1024, N = 1024;
    __shared__ _Float16 SH[6144];   // As 64x32 (4KB) | Bs 128x32 (8KB)
    _Float16* As = SH;
    _Float16* Bs = SH + 2048;
    const int t = threadIdx.x;
    const int lane = t & 63, w = t >> 6;
    const int l15 = lane & 15, quad = lane >> 4;
    const int wm = w >> 1, wn = w & 1;
    const int m0 = blockIdx.y * 64, n0 = blockIdx.x * 128;

    floatx4 acc[2][4];
    const floatx4 zf = {0.f, 0.f, 0.f, 0.f};
#pragma unroll
    for (int i = 0; i < 2; ++i)
#pragma unroll
        for (int j = 0; j < 4; ++j) acc[i][j] = zf;

    for (int kt = 0; kt < K; kt += 32) {
        __syncthreads();
        {   // A: 256 chunks of 16B
            int row = t >> 2, kc = t & 3;
            gl_lds16(&A[(size_t)(m0 + row) * K + kt + kc * 8], &As[t * 8]);
        }
#pragma unroll
        for (int it = 0; it < 2; ++it) {    // B: 512 chunks of 16B
            int cc = it * 256 + t;
            int row = cc >> 2, kc = cc & 3;
            gl_lds16(&B[(size_t)(n0 + row) * K + kt + kc * 8], &Bs[cc * 8]);
        }
        __syncthreads();
        half8 af[2], bfr[4];
#pragma unroll
        for (int i = 0; i < 2; ++i)
            af[i] = *(const half8*)&As[(wm * 32 + i * 16 + l15) * 32 + quad * 8];
#pragma unroll
        for (int i = 0; i < 4; ++i)
            bfr[i] = *(const half8*)&Bs[(wn * 64 + i * 16 + l15) * 32 + quad * 8];
#pragma unroll
        for (int mi = 0; mi < 2; ++mi)
#pragma unroll
            for (int ni = 0; ni < 4; ++ni)
                acc[mi][ni] = __builtin_amdgcn_mfma_f32_16x16x32_f16(af[mi], bfr[ni],
                                                                     acc[mi][ni], 0, 0, 0);
    }

#pragma unroll
    for (int mi = 0; mi < 2; ++mi) {
#pragma unroll
        for (int ni = 0; ni < 4; ++ni) {
            int col = n0 + wn * 64 + ni * 16 + l15;
            float bv = bias[col];
#pragma unroll
            for (int r = 0; r < 4; ++r) {
                int row = m0 + wm * 32 + mi * 16 + quad * 4 + r;
                C[(size_t)row * N + col] = acc[mi][ni][r] + bv;
            }
        }
    }
}

// ---------------- fused two-pass stablemax attention (S^T form, 4 waves) ---------
// MEASURED LOCAL OPTIMUM (r14: 87.5-88.5 us). Perturbations tested & rejected:
// 512-thr (r5), KT=128 (r9/r17), dbuf (r13), q-tile 64 (r16) — all slower/neutral.
// grid (S/128, B*H), 256 threads. Wave w owns 32 q rows (w*32 + nh*16 + l15).
// Q pre-scaled by 0.125 in registers; s3 in packed fp16; P never touches LDS
// (permuted-key PV: key(c,quad,j) = c*32 + (j>>2)*16 + quad*4 + (j&3)).
__global__ __launch_bounds__(256) void attn_kernel(const _Float16* __restrict__ qh,
                                                   const _Float16* __restrict__ kh,
                                                   const _Float16* __restrict__ vth,
                                                   _Float16* __restrict__ out) {
    __shared__ _Float16 SM[2 * 64 * 72];   // Ks | VTs (9 KB each); reused as O-stage
    _Float16* Ks = SM;
    _Float16* VTs = SM + 64 * 72;

    const int t = threadIdx.x;
    const int lane = t & 63, w = t >> 6;
    const int l15 = lane & 15, quad = lane >> 4;
    const int q0 = blockIdx.x * 128;
    const int bh = blockIdx.y;
    const int b = bh >> 4, h = bh & 15;

    const _Float16* Qp = qh + (size_t)bh * 131072 + q0 * 64;
    const _Float16* Kp = kh + (size_t)bh * 131072;
    const _Float16* VTp = vth + (size_t)bh * 131072;

    const floatx4 zf = {0.f, 0.f, 0.f, 0.f};

    half8 qf[2][2];   // [nh][kk], pre-scaled by 0.125
#pragma unroll
    for (int nh = 0; nh < 2; ++nh)
#pragma unroll
        for (int kk = 0; kk < 2; ++kk) {
            half8 q = *(const half8*)&Qp[(w * 32 + nh * 16 + l15) * 64 + kk * 32 + quad * 8];
#pragma unroll
            for (int j = 0; j < 8; ++j) q[j] = q[j] * (_Float16)0.125f;
            qf[nh][kk] = q;
        }

    // ---------------- pass 1: row max over (scaled) scores --------------------
    float rmax[2] = {-1.0e30f, -1.0e30f};

    for (int kt = 0; kt < 2048; kt += 64) {
        __syncthreads();
#pragma unroll
        for (int it = 0; it < 2; ++it) {
            int cc = it * 256 + t;
            int r = cc >> 3, c8 = cc & 7;
            *(half8*)&Ks[r * 72 + c8 * 8] = *(const half8*)&Kp[kt * 64 + cc * 8];
        }
        __syncthreads();
        floatx4 sa[4][2];
#pragma unroll
        for (int T = 0; T < 4; ++T) { sa[T][0] = zf; sa[T][1] = zf; }
#pragma unroll
        for (int kk = 0; kk < 2; ++kk) {
            half8 kf[4];
#pragma unroll
            for (int T = 0; T < 4; ++T)
                kf[T] = *(const half8*)&Ks[(T * 16 + l15) * 72 + kk * 32 + quad * 8];
#pragma unroll
            for (int T = 0; T < 4; ++T)
#pragma unroll
                for (int nh = 0; nh < 2; ++nh)
                    sa[T][nh] = __builtin_amdgcn_mfma_f32_16x16x32_f16(kf[T], qf[nh][kk],
                                                                      sa[T][nh], 0, 0, 0);
        }
#pragma unroll
        for (int T = 0; T < 4; ++T)
#pragma unroll
            for (int nh = 0; nh < 2; ++nh)
#pragma unroll
                for (int r = 0; r < 4; ++r)
                    rmax[nh] = fmaxf(rmax[nh], sa[T][nh][r]);
    }
#pragma unroll
    for (int nh = 0; nh < 2; ++nh) {
        rmax[nh] = fmaxf(rmax[nh], __shfl_xor(rmax[nh], 16, 64));
        rmax[nh] = fmaxf(rmax[nh], __shfl_xor(rmax[nh], 32, 64));
    }
    const float xm[2] = {-rmax[0], -rmax[1]};

    // ---------------- pass 2: p = s3(x); Sum p; P·V ---------------------------
    const half2v cA = {(_Float16)(-1.0f / 6.0f), (_Float16)(-1.0f / 6.0f)};
    const half2v cB = {(_Float16)0.5f, (_Float16)0.5f};
    const half2v cC = {(_Float16)-1.0f, (_Float16)-1.0f};
    const half2v cD = {(_Float16)1.0f, (_Float16)1.0f};

    float rsum[2] = {0.f, 0.f};
    floatx4 oacc[4][2];
#pragma unroll
    for (int i = 0; i < 4; ++i) { oacc[i][0] = zf; oacc[i][1] = zf; }

    for (int kt = 0; kt < 2048; kt += 64) {
        __syncthreads();
#pragma unroll
        for (int it = 0; it < 2; ++it) {
            int cc = it * 256 + t;
            int r = cc >> 3, c8 = cc & 7;
            *(half8*)&Ks[r * 72 + c8 * 8] = *(const half8*)&Kp[kt * 64 + cc * 8];
            *(half8*)&VTs[r * 72 + c8 * 8] =
                *(const half8*)&VTp[(size_t)r * 2048 + kt + c8 * 8];
        }
        __syncthreads();
        floatx4 sa[4][2];
#pragma unroll
        for (int T = 0; T < 4; ++T) { sa[T][0] = zf; sa[T][1] = zf; }
#pragma unroll
        for (int kk = 0; kk < 2; ++kk) {
            half8 kf[4];
#pragma unroll
            for (int T = 0; T < 4; ++T)
                kf[T] = *(const half8*)&Ks[(T * 16 + l15) * 72 + kk * 32 + quad * 8];
#pragma unroll
            for (int T = 0; T < 4; ++T)
#pragma unroll
                for (int nh = 0; nh < 2; ++nh)
                    sa[T][nh] = __builtin_amdgcn_mfma_f32_16x16x32_f16(kf[T], qf[nh][kk],
                                                                      sa[T][nh], 0, 0, 0);
        }
        // PV with permuted key order; s3 in packed fp16 straight into pb
#pragma unroll
        for (int c = 0; c < 2; ++c) {
            half8 vf[4];
#pragma unroll
            for (int di = 0; di < 4; ++di) {
                half4 lo = *(const half4*)&VTs[(di * 16 + l15) * 72 + c * 32 + 4 * quad];
                half4 hi = *(const half4*)&VTs[(di * 16 + l15) * 72 + c * 32 + 16 + 4 * quad];
                half8 vv;
#pragma unroll
                for (int j = 0; j < 4; ++j) { vv[j] = lo[j]; vv[j + 4] = hi[j]; }
                vf[di] = vv;
            }
#pragma unroll
            for (int nh = 0; nh < 2; ++nh) {
                half8 pb;
#pragma unroll
                for (int m = 0; m < 4; ++m) {
                    int T = 2 * c + (m >> 1);
                    int r0 = (m & 1) * 2;
                    half2v x2 = cvt_pk(sa[T][nh][r0] + xm[nh],
                                       sa[T][nh][r0 + 1] + xm[nh]);
                    half2v hp = __builtin_elementwise_fma(x2, cA, cB);
                    hp = __builtin_elementwise_fma(x2, hp, cC);
                    hp = __builtin_elementwise_fma(x2, hp, cD);
                    half2v p2 = rcp2(hp);
                    rsum[nh] = dot2acc(p2, rsum[nh]);
                    pb[2 * m] = p2[0];
                    pb[2 * m + 1] = p2[1];
                }
#pragma unroll
                for (int di = 0; di < 4; ++di)
                    oacc[di][nh] = __builtin_amdgcn_mfma_f32_16x16x32_f16(vf[di], pb,
                                                                         oacc[di][nh], 0, 0, 0);
            }
        }
    }

#pragma unroll
    for (int nh = 0; nh < 2; ++nh) {
        rsum[nh] += __shfl_xor(rsum[nh], 16, 64);
        rsum[nh] += __shfl_xor(rsum[nh], 32, 64);
    }
    const float inv[2] = {1.0f / rsum[0], 1.0f / rsum[1]};

    __syncthreads();
    _Float16* Os = SM;
#pragma unroll
    for (int di = 0; di < 4; ++di) {
#pragma unroll
        for (int nh = 0; nh < 2; ++nh) {
            half4 hv;
#pragma unroll
            for (int r = 0; r < 4; ++r) hv[r] = (_Float16)(oacc[di][nh][r] * inv[nh]);
            *(half4*)&Os[(w * 32 + nh * 16 + l15) * 72 + di * 16 + quad * 4] = hv;
        }
    }
    __syncthreads();
    _Float16* Op = out + (size_t)(b * 2048 + q0) * 1024 + h * 64;
#pragma unroll
    for (int it = 0; it < 4; ++it) {
        int cc = it * 256 + t;
        int r = cc >> 3, c8 = cc & 7;
        *(half8*)&Op[(size_t)r * 1024 + c8 * 8] = *(const half8*)&Os[r * 72 + c8 * 8];
    }
}

// ---------------- launch ---------------------------------------------------------
extern "C" void kernel_launch(void* const* d_in, const int* in_sizes, int n_in,
                              void* d_out, int out_size, void* d_ws, size_t ws_size,
                              hipStream_t stream) {
    const float* x_f = (const float*)d_in[0];     // [2,2048,1024] fp32
    const float* wqkv_f = (const float*)d_in[1];  // [3072,1024] fp32
    const float* wout_f = (const float*)d_in[2];  // [1024,1024] fp32
    const float* bias_f = (const float*)d_in[3];  // [1024] fp32

    // workspace: 38 MB, with aliasing (aoh reuses xh; woh reuses wqh).
    // ORDERING CONSTRAINT: woh is written only AFTER gemm_qkv consumes wqh.
    char* ws = (char*)d_ws;
    _Float16* xh = (_Float16*)(ws);                   // [4096][1024] f16, 8 MB
    _Float16* aoh = xh;                               // alias: live after gemm_qkv
    _Float16* wqh = (_Float16*)(ws + 8388608);        // [3072][1024] f16, 6 MB
    _Float16* woh = wqh;                              // alias: live after gemm_qkv
    _Float16* qh = (_Float16*)(ws + 14680064);        // [32][2048][64] f16, 8 MB
    _Float16* kh = (_Float16*)(ws + 23068672);        // [32][2048][64] f16, 8 MB
    _Float16* vth = (_Float16*)(ws + 31457280);       // [32][64][2048] f16, 8 MB

    cvt_xw<<<7168, 256, 0, stream>>>((const floatx4*)x_f, (const floatx4*)wqkv_f,
                                     (half4*)xh, (half4*)wqh);
    gemm_qkv<<<dim3(24, 32), 256, 0, stream>>>(xh, wqh, qh, kh, vth);
    cvt_f32_f16<<<1024, 256, 0, stream>>>((const floatx4*)wout_f, (half4*)woh, 262144);
    attn_kernel<<<dim3(16, 32), 256, 0, stream>>>(qh, kh, vth, aoh);
    gemm_out<<<dim3(8, 64), 256, 0, stream>>>(aoh, woh, (float*)d_out, bias_f);
}

// Round 19
// 212.672 us; speedup vs baseline: 1.1726x; 1.0123x over previous
//
#include <hip/hip_runtime.h>

typedef _Float16 half8 __attribute__((ext_vector_type(8)));
typedef _Float16 half4 __attribute__((ext_vector_type(4)));
typedef _Float16 half2v __attribute__((ext_vector_type(2)));
typedef float floatx4 __attribute__((ext_vector_type(4)));
typedef unsigned int uint2v __attribute__((ext_vector_type(2)));
typedef unsigned int uint4v __attribute__((ext_vector_type(4)));

__device__ __forceinline__ void gl_lds16(const _Float16* g, _Float16* l) {
    __builtin_amdgcn_global_load_lds(
        (const __attribute__((address_space(1))) void*)g,
        (__attribute__((address_space(3))) void*)l, 16, 0, 0);
}

__device__ __forceinline__ half2v cvt_pk(float a, float b) {
    return __builtin_bit_cast(half2v, __builtin_amdgcn_cvt_pkrtz(a, b));
}

__device__ __forceinline__ half2v rcp2(half2v d) {
#if __has_builtin(__builtin_amdgcn_rcph)
    half2v r;
    r[0] = __builtin_amdgcn_rcph(d[0]);
    r[1] = __builtin_amdgcn_rcph(d[1]);
    return r;
#else
    half2v r;
    r[0] = (_Float16)__builtin_amdgcn_rcpf((float)d[0]);
    r[1] = (_Float16)__builtin_amdgcn_rcpf((float)d[1]);
    return r;
#endif
}

__device__ __forceinline__ float dot2acc(half2v a, float acc) {
#if __has_builtin(__builtin_amdgcn_fdot2)
    const half2v one = {(_Float16)1.0f, (_Float16)1.0f};
    return __builtin_amdgcn_fdot2(a, one, acc, false);
#else
    return acc + (float)a[0] + (float)a[1];
#endif
}

// concat 4 packed half2 (each one dword) into a half8 — no element inserts
__device__ __forceinline__ half8 from4(half2v a, half2v b, half2v c, half2v d) {
    uint4v u = {__builtin_bit_cast(unsigned int, a), __builtin_bit_cast(unsigned int, b),
                __builtin_bit_cast(unsigned int, c), __builtin_bit_cast(unsigned int, d)};
    return __builtin_bit_cast(half8, u);
}

// concat two half4 (two dword-pairs) into a half8 — no element inserts
__device__ __forceinline__ half8 from_lohi(half4 lo, half4 hi) {
    uint2v l = __builtin_bit_cast(uint2v, lo);
    uint2v h = __builtin_bit_cast(uint2v, hi);
    uint4v u = {l[0], l[1], h[0], h[1]};
    return __builtin_bit_cast(half8, u);
}

// ---------------- fp32 -> fp16 convert: x and w_qkv fused (runs BEFORE gemm_qkv) -
__global__ __launch_bounds__(256) void cvt_xw(const floatx4* __restrict__ x,
                                              const floatx4* __restrict__ wq,
                                              half4* __restrict__ xh,
                                              half4* __restrict__ wqh) {
    int i = blockIdx.x * 256 + threadIdx.x;   // 0..1835007
    floatx4 v;
    half4 h;
    if (i < 1048576) {
        v = x[i];
#pragma unroll
        for (int j = 0; j < 4; ++j) h[j] = (_Float16)v[j];
        xh[i] = h;
    } else {
        int j4 = i - 1048576;
        v = wq[j4];
#pragma unroll
        for (int j = 0; j < 4; ++j) h[j] = (_Float16)v[j];
        wqh[j4] = h;
    }
}

// wout cvt — MUST run after gemm_qkv (woh aliases wqh)
__global__ __launch_bounds__(256) void cvt_f32_f16(const floatx4* __restrict__ in,
                                                   half4* __restrict__ out, int n4) {
    int i = blockIdx.x * 256 + threadIdx.x;
    if (i >= n4) return;
    floatx4 v = in[i];
    half4 h;
#pragma unroll
    for (int j = 0; j < 4; ++j) h[j] = (_Float16)v[j];
    out[i] = h;
}

// ---------------- GEMM1: qkv = xh @ wqh^T -> head-major q/k/vt (fp16 in/out) -----
// M=4096, N=3072, K=1024. 128x128 tile, BK=32, 256 thr, DMA staging.
__global__ __launch_bounds__(256) void gemm_qkv(const _Float16* __restrict__ A,
                                                const _Float16* __restrict__ B,
                                                _Float16* __restrict__ qh,
                                                _Float16* __restrict__ kh,
                                                _Float16* __restrict__ vth) {
    const int K = 1024;
    __shared__ _Float16 SH[128 * 68];   // As 8KB | Bs 8KB; epilogue 128x68
    _Float16* As = SH;
    _Float16* Bs = SH + 4096;
    const int t = threadIdx.x;
    const int lane = t & 63, w = t >> 6;
    const int l15 = lane & 15, quad = lane >> 4;
    const int wm = w >> 1, wn = w & 1;
    const int m0 = blockIdx.y * 128, n0 = blockIdx.x * 128;

    floatx4 acc[4][4];
    const floatx4 zf = {0.f, 0.f, 0.f, 0.f};
#pragma unroll
    for (int i = 0; i < 4; ++i)
#pragma unroll
        for (int j = 0; j < 4; ++j) acc[i][j] = zf;

    for (int kt = 0; kt < K; kt += 32) {
        __syncthreads();
#pragma unroll
        for (int it = 0; it < 2; ++it) {    // 512 chunks of 16B per matrix
            int cc = it * 256 + t;
            int row = cc >> 2, kc = cc & 3;
            gl_lds16(&A[(size_t)(m0 + row) * K + kt + kc * 8], &As[cc * 8]);
            gl_lds16(&B[(size_t)(n0 + row) * K + kt + kc * 8], &Bs[cc * 8]);
        }
        __syncthreads();
        half8 af[4], bfr[4];
#pragma unroll
        for (int i = 0; i < 4; ++i)
            af[i] = *(const half8*)&As[(wm * 64 + i * 16 + l15) * 32 + quad * 8];
#pragma unroll
        for (int i = 0; i < 4; ++i)
            bfr[i] = *(const half8*)&Bs[(wn * 64 + i * 16 + l15) * 32 + quad * 8];
#pragma unroll
        for (int mi = 0; mi < 4; ++mi)
#pragma unroll
            for (int ni = 0; ni < 4; ++ni)
                acc[mi][ni] = __builtin_amdgcn_mfma_f32_16x16x32_f16(af[mi], bfr[ni],
                                                                     acc[mi][ni], 0, 0, 0);
    }

    // ---- epilogue: two 128x64 col-halves staged through LDS, coalesced writes ----
    const int b = m0 >> 11, s0 = m0 & 2047;
#pragma unroll
    for (int hf = 0; hf < 2; ++hf) {
        __syncthreads();
        if (wn == hf) {
#pragma unroll
            for (int mi = 0; mi < 4; ++mi)
#pragma unroll
                for (int ni = 0; ni < 4; ++ni)
#pragma unroll
                    for (int r = 0; r < 4; ++r)
                        SH[(wm * 64 + mi * 16 + quad * 4 + r) * 68 + ni * 16 + l15] =
                            (_Float16)acc[mi][ni][r];
        }
        __syncthreads();
        const int cbase = n0 + hf * 64;
        if (n0 < 2048) {
            const int hh = (cbase & 1023) >> 6;
            _Float16* dst = (n0 < 1024 ? qh : kh) + (size_t)((b << 4) | hh) * 131072;
#pragma unroll
            for (int it = 0; it < 4; ++it) {
                int cc = it * 256 + t;
                int r = cc >> 3, c8 = cc & 7;
                half4 lo = *(const half4*)&SH[r * 68 + c8 * 8];
                half4 hi = *(const half4*)&SH[r * 68 + c8 * 8 + 4];
                *(half8*)&dst[(size_t)(s0 + r) * 64 + c8 * 8] = from_lohi(lo, hi);
            }
        } else {
            const int hh = (cbase - 2048) >> 6;
            _Float16* dst = vth + (size_t)((b << 4) | hh) * 131072;
#pragma unroll
            for (int it = 0; it < 4; ++it) {
                int cc = it * 256 + t;
                int d = cc >> 4, s8 = cc & 15;
                half8 v;
#pragma unroll
                for (int j = 0; j < 8; ++j) v[j] = SH[(s8 * 8 + j) * 68 + d];
                *(half8*)&dst[(size_t)d * 2048 + s0 + s8 * 8] = v;
            }
        }
    }
}

// ---------------- GEMM2: out = aoh @ woh^T + b_out -> fp32 -----------------------
// M=4096, N=1024, K=1024. 64x128 tile, BK=32, 256 thr, DMA staging.
__global__ __launch_bounds__(256) void gemm_out(const _Float16* __restrict__ A,
                                                const _Float16* __restrict__ B,
                                                float* __restrict__ C,
                                                const float* __restrict__ bias) {
    const int K = 1024, N = 1024;
    __shared__ _Float16 SH[6144];   // As 64x32 (4KB) | Bs 128x32 (8KB)
    _Float16* As = SH;
    _Float16* Bs = SH + 2048;
    const int t = threadIdx.x;
    const int lane = t & 63, w = t >> 6;
    const int l15 = lane & 15, quad = lane >> 4;
    const int wm = w >> 1, wn = w & 1;
    const int m0 = blockIdx.y * 64, n0 = blockIdx.x * 128;

    floatx4 acc[2][4];
    const floatx4 zf = {0.f, 0.f, 0.f, 0.f};
#pragma unroll
    for (int i = 0; i < 2; ++i)
#pragma unroll
        for (int j = 0; j < 4; ++j) acc[i][j] = zf;

    for (int kt = 0; kt < K; kt += 32) {
        __syncthreads();
        {   // A: 256 chunks of 16B
            int row = t >> 2, kc = t & 3;
            gl_lds16(&A[(size_t)(m0 + row) * K + kt + kc * 8], &As[t * 8]);
        }
#pragma unroll
        for (int it = 0; it < 2; ++it) {    // B: 512 chunks of 16B
            int cc = it * 256 + t;
            int row = cc >> 2, kc = cc & 3;
            gl_lds16(&B[(size_t)(n0 + row) * K + kt + kc * 8], &Bs[cc * 8]);
        }
        __syncthreads();
        half8 af[2], bfr[4];
#pragma unroll
        for (int i = 0; i < 2; ++i)
            af[i] = *(const half8*)&As[(wm * 32 + i * 16 + l15) * 32 + quad * 8];
#pragma unroll
        for (int i = 0; i < 4; ++i)
            bfr[i] = *(const half8*)&Bs[(wn * 64 + i * 16 + l15) * 32 + quad * 8];
#pragma unroll
        for (int mi = 0; mi < 2; ++mi)
#pragma unroll
            for (int ni = 0; ni < 4; ++ni)
                acc[mi][ni] = __builtin_amdgcn_mfma_f32_16x16x32_f16(af[mi], bfr[ni],
                                                                     acc[mi][ni], 0, 0, 0);
    }

#pragma unroll
    for (int mi = 0; mi < 2; ++mi) {
#pragma unroll
        for (int ni = 0; ni < 4; ++ni) {
            int col = n0 + wn * 64 + ni * 16 + l15;
            float bv = bias[col];
#pragma unroll
            for (int r = 0; r < 4; ++r) {
                int row = m0 + wm * 32 + mi * 16 + quad * 4 + r;
                C[(size_t)row * N + col] = acc[mi][ni][r] + bv;
            }
        }
    }
}

// ---------------- fused two-pass stablemax attention (S^T form, 4 waves) ---------
// MEASURED LOCAL OPTIMUM structure (r14/r18: 87.5-88.5 us). This round: packed
// dword-level vector construction (from4/from_lohi) instead of element inserts —
// semantics identical, targets suspected v_bfi/insert codegen overhead.
// grid (S/128, B*H), 256 threads. Wave w owns 32 q rows (w*32 + nh*16 + l15).
// Q pre-scaled by 0.125 in registers; s3 in packed fp16; P never touches LDS
// (permuted-key PV: key(c,quad,j) = c*32 + (j>>2)*16 + quad*4 + (j&3)).
__global__ __launch_bounds__(256) void attn_kernel(const _Float16* __restrict__ qh,
                                                   const _Float16* __restrict__ kh,
                                                   const _Float16* __restrict__ vth,
                                                   _Float16* __restrict__ out) {
    __shared__ _Float16 SM[2 * 64 * 72];   // Ks | VTs (9 KB each); reused as O-stage
    _Float16* Ks = SM;
    _Float16* VTs = SM + 64 * 72;

    const int t = threadIdx.x;
    const int lane = t & 63, w = t >> 6;
    const int l15 = lane & 15, quad = lane >> 4;
    const int q0 = blockIdx.x * 128;
    const int bh = blockIdx.y;
    const int b = bh >> 4, h = bh & 15;

    const _Float16* Qp = qh + (size_t)bh * 131072 + q0 * 64;
    const _Float16* Kp = kh + (size_t)bh * 131072;
    const _Float16* VTp = vth + (size_t)bh * 131072;

    const floatx4 zf = {0.f, 0.f, 0.f, 0.f};

    half8 qf[2][2];   // [nh][kk], pre-scaled by 0.125
#pragma unroll
    for (int nh = 0; nh < 2; ++nh)
#pragma unroll
        for (int kk = 0; kk < 2; ++kk) {
            half8 q = *(const half8*)&Qp[(w * 32 + nh * 16 + l15) * 64 + kk * 32 + quad * 8];
#pragma unroll
            for (int j = 0; j < 8; ++j) q[j] = q[j] * (_Float16)0.125f;
            qf[nh][kk] = q;
        }

    // ---------------- pass 1: row max over (scaled) scores --------------------
    float rmax[2] = {-1.0e30f, -1.0e30f};

    for (int kt = 0; kt < 2048; kt += 64) {
        __syncthreads();
#pragma unroll
        for (int it = 0; it < 2; ++it) {
            int cc = it * 256 + t;
            int r = cc >> 3, c8 = cc & 7;
            *(half8*)&Ks[r * 72 + c8 * 8] = *(const half8*)&Kp[kt * 64 + cc * 8];
        }
        __syncthreads();
        floatx4 sa[4][2];
#pragma unroll
        for (int T = 0; T < 4; ++T) { sa[T][0] = zf; sa[T][1] = zf; }
#pragma unroll
        for (int kk = 0; kk < 2; ++kk) {
            half8 kf[4];
#pragma unroll
            for (int T = 0; T < 4; ++T)
                kf[T] = *(const half8*)&Ks[(T * 16 + l15) * 72 + kk * 32 + quad * 8];
#pragma unroll
            for (int T = 0; T < 4; ++T)
#pragma unroll
                for (int nh = 0; nh < 2; ++nh)
                    sa[T][nh] = __builtin_amdgcn_mfma_f32_16x16x32_f16(kf[T], qf[nh][kk],
                                                                      sa[T][nh], 0, 0, 0);
        }
#pragma unroll
        for (int T = 0; T < 4; ++T)
#pragma unroll
            for (int nh = 0; nh < 2; ++nh)
#pragma unroll
                for (int r = 0; r < 4; ++r)
                    rmax[nh] = fmaxf(rmax[nh], sa[T][nh][r]);
    }
#pragma unroll
    for (int nh = 0; nh < 2; ++nh) {
        rmax[nh] = fmaxf(rmax[nh], __shfl_xor(rmax[nh], 16, 64));
        rmax[nh] = fmaxf(rmax[nh], __shfl_xor(rmax[nh], 32, 64));
    }
    const float xm[2] = {-rmax[0], -rmax[1]};

    // ---------------- pass 2: p = s3(x); Sum p; P·V ---------------------------
    const half2v cA = {(_Float16)(-1.0f / 6.0f), (_Float16)(-1.0f / 6.0f)};
    const half2v cB = {(_Float16)0.5f, (_Float16)0.5f};
    const half2v cC = {(_Float16)-1.0f, (_Float16)-1.0f};
    const half2v cD = {(_Float16)1.0f, (_Float16)1.0f};

    float rsum[2] = {0.f, 0.f};
    floatx4 oacc[4][2];
#pragma unroll
    for (int i = 0; i < 4; ++i) { oacc[i][0] = zf; oacc[i][1] = zf; }

    for (int kt = 0; kt < 2048; kt += 64) {
        __syncthreads();
#pragma unroll
        for (int it = 0; it < 2; ++it) {
            int cc = it * 256 + t;
            int r = cc >> 3, c8 = cc & 7;
            *(half8*)&Ks[r * 72 + c8 * 8] = *(const half8*)&Kp[kt * 64 + cc * 8];
            *(half8*)&VTs[r * 72 + c8 * 8] =
                *(const half8*)&VTp[(size_t)r * 2048 + kt + c8 * 8];
        }
        __syncthreads();
        floatx4 sa[4][2];
#pragma unroll
        for (int T = 0; T < 4; ++T) { sa[T][0] = zf; sa[T][1] = zf; }
#pragma unroll
        for (int kk = 0; kk < 2; ++kk) {
            half8 kf[4];
#pragma unroll
            for (int T = 0; T < 4; ++T)
                kf[T] = *(const half8*)&Ks[(T * 16 + l15) * 72 + kk * 32 + quad * 8];
#pragma unroll
            for (int T = 0; T < 4; ++T)
#pragma unroll
                for (int nh = 0; nh < 2; ++nh)
                    sa[T][nh] = __builtin_amdgcn_mfma_f32_16x16x32_f16(kf[T], qf[nh][kk],
                                                                      sa[T][nh], 0, 0, 0);
        }
        // PV with permuted key order; s3 in packed fp16 straight into pb
#pragma unroll
        for (int c = 0; c < 2; ++c) {
            half8 vf[4];
#pragma unroll
            for (int di = 0; di < 4; ++di) {
                half4 lo = *(const half4*)&VTs[(di * 16 + l15) * 72 + c * 32 + 4 * quad];
                half4 hi = *(const half4*)&VTs[(di * 16 + l15) * 72 + c * 32 + 16 + 4 * quad];
                vf[di] = from_lohi(lo, hi);
            }
#pragma unroll
            for (int nh = 0; nh < 2; ++nh) {
                half2v p2m[4];
#pragma unroll
                for (int m = 0; m < 4; ++m) {
                    int T = 2 * c + (m >> 1);
                    int r0 = (m & 1) * 2;
                    half2v x2 = cvt_pk(sa[T][nh][r0] + xm[nh],
                                       sa[T][nh][r0 + 1] + xm[nh]);
                    half2v hp = __builtin_elementwise_fma(x2, cA, cB);
                    hp = __builtin_elementwise_fma(x2, hp, cC);
                    hp = __builtin_elementwise_fma(x2, hp, cD);
                    half2v p2 = rcp2(hp);
                    rsum[nh] = dot2acc(p2, rsum[nh]);
                    p2m[m] = p2;
                }
                half8 pb = from4(p2m[0], p2m[1], p2m[2], p2m[3]);
#pragma unroll
                for (int di = 0; di < 4; ++di)
                    oacc[di][nh] = __builtin_amdgcn_mfma_f32_16x16x32_f16(vf[di], pb,
                                                                         oacc[di][nh], 0, 0, 0);
            }
        }
    }

#pragma unroll
    for (int nh = 0; nh < 2; ++nh) {
        rsum[nh] += __shfl_xor(rsum[nh], 16, 64);
        rsum[nh] += __shfl_xor(rsum[nh], 32, 64);
    }
    const float inv[2] = {1.0f / rsum[0], 1.0f / rsum[1]};

    __syncthreads();
    _Float16* Os = SM;
#pragma unroll
    for (int di = 0; di < 4; ++di) {
#pragma unroll
        for (int nh = 0; nh < 2; ++nh) {
            half4 hv;
#pragma unroll
            for (int r = 0; r < 4; ++r) hv[r] = (_Float16)(oacc[di][nh][r] * inv[nh]);
            *(half4*)&Os[(w * 32 + nh * 16 + l15) * 72 + di * 16 + quad * 4] = hv;
        }
    }
    __syncthreads();
    _Float16* Op = out + (size_t)(b * 2048 + q0) * 1024 + h * 64;
#pragma unroll
    for (int it = 0; it < 4; ++it) {
        int cc = it * 256 + t;
        int r = cc >> 3, c8 = cc & 7;
        *(half8*)&Op[(size_t)r * 1024 + c8 * 8] = *(const half8*)&Os[r * 72 + c8 * 8];
    }
}

// ---------------- launch ---------------------------------------------------------
extern "C" void kernel_launch(void* const* d_in, const int* in_sizes, int n_in,
                              void* d_out, int out_size, void* d_ws, size_t ws_size,
                              hipStream_t stream) {
    const float* x_f = (const float*)d_in[0];     // [2,2048,1024] fp32
    const float* wqkv_f = (const float*)d_in[1];  // [3072,1024] fp32
    const float* wout_f = (const float*)d_in[2];  // [1024,1024] fp32
    const float* bias_f = (const float*)d_in[3];  // [1024] fp32

    // workspace: 38 MB, with aliasing (aoh reuses xh; woh reuses wqh).
    // ORDERING CONSTRAINT: woh is written only AFTER gemm_qkv consumes wqh.
    char* ws = (char*)d_ws;
    _Float16* xh = (_Float16*)(ws);                   // [4096][1024] f16, 8 MB
    _Float16* aoh = xh;                               // alias: live after gemm_qkv
    _Float16* wqh = (_Float16*)(ws + 8388608);        // [3072][1024] f16, 6 MB
    _Float16* woh = wqh;                              // alias: live after gemm_qkv
    _Float16* qh = (_Float16*)(ws + 14680064);        // [32][2048][64] f16, 8 MB
    _Float16* kh = (_Float16*)(ws + 23068672);        // [32][2048][64] f16, 8 MB
    _Float16* vth = (_Float16*)(ws + 31457280);       // [32][64][2048] f16, 8 MB

    cvt_xw<<<7168, 256, 0, stream>>>((const floatx4*)x_f, (const floatx4*)wqkv_f,
                                     (half4*)xh, (half4*)wqh);
    gemm_qkv<<<dim3(24, 32), 256, 0, stream>>>(xh, wqh, qh, kh, vth);
    cvt_f32_f16<<<1024, 256, 0, stream>>>((const floatx4*)wout_f, (half4*)woh, 262144);
    attn_kernel<<<dim3(16, 32), 256, 0, stream>>>(qh, kh, vth, aoh);
    gemm_out<<<dim3(8, 64), 256, 0, stream>>>(aoh, woh, (float*)d_out, bias_f);
}